// Round 20
// baseline (67.262 us; speedup 1.0000x reference)
//
#include <hip/hip_runtime.h>
#include <hip/hip_bf16.h>

typedef short bf16x8 __attribute__((ext_vector_type(8)));
typedef float f32x4  __attribute__((ext_vector_type(4)));

__device__ __forceinline__ unsigned short f2bf(float f) {
    union { __hip_bfloat16 b; unsigned short u; } v;
    v.b = __hip_bfloat16(f);          // native RNE cvt (pairs into v_cvt_pk_bf16_f32)
    return v.u;
}

// MFMA pinned to arch VGPRs via inline asm -> zero AGPRs -> the full
// __launch_bounds__ budget is arch registers (r13: no spill, 2 WG/CU).
// VOLATILE is load-bearing (r14: non-volatile -> scheduler sank MFMAs -> NaN).
// s_nop 1 embedded covers compiler-inserted VALU writes before the MFMA (r12).
// (512,4) is load-bearing: (512,8)'s 64-reg cap forced mid-cluster spills whose
// scratch code is hazard-unprotected around asm MFMAs (r17: absmax 1.27).
__device__ __forceinline__ f32x4 mfma_bf16(bf16x8 a, bf16x8 b, f32x4 c) {
    asm volatile("s_nop 1\n\tv_mfma_f32_16x16x32_bf16 %0, %1, %2, %0"
                 : "+v"(c) : "v"(a), "v"(b));
    return c;
}

// Cluster-boundary fence: 16 wait states >= MFMA-write -> VALU-read hazard.
__device__ __forceinline__ void mfma_fence() {
    __builtin_amdgcn_sched_barrier(0);
    asm volatile("s_nop 7\n\ts_nop 7");
    __builtin_amdgcn_sched_barrier(0);
}

// T5: boost wave priority while issuing MFMA clusters. With 2 independent
// WGs/CU and 8 waves drifting between barriers, waves are at DIFFERENT phases
// (the regime where setprio pays: m191 attn +4-7%; null only in lockstep).
__device__ __forceinline__ void prio_hi() { __builtin_amdgcn_s_setprio(1); }
__device__ __forceinline__ void prio_lo() { __builtin_amdgcn_s_setprio(0); }

// pack two f32x4 acc tiles (m-tile 0, m-tile 1) into one bf16 fragment under
// the shared k-bijection pi(g,j) = {4g+j | j<4} u {16+4g+(j-4) | j>=4}
__device__ __forceinline__ bf16x8 pack2(f32x4 lo, f32x4 hi) {
    bf16x8 r;
    r[0] = (short)f2bf(lo[0]); r[1] = (short)f2bf(lo[1]);
    r[2] = (short)f2bf(lo[2]); r[3] = (short)f2bf(lo[3]);
    r[4] = (short)f2bf(hi[0]); r[5] = (short)f2bf(hi[1]);
    r[6] = (short)f2bf(hi[2]); r[7] = (short)f2bf(hi[3]);
    return r;
}

// ---------------- prep: weights -> MFMA-fragment-linear bf16 layout ----------------
// slot s = (((mat*8 + h)*2 + t)*8 + kk)*64 + lane ; each slot = 8 bf16 (16 B).
// content: W[k][n] for n = h*32 + t*16 + (lane&15), k = kk*32 + (lane>>4)*8 + j.
__global__ __launch_bounds__(256) void prep_weights(
    const float* __restrict__ wq, const float* __restrict__ wk,
    const float* __restrict__ wv, const float* __restrict__ wo,
    unsigned short* __restrict__ wt)
{
    const int s = blockIdx.x * 256 + threadIdx.x;   // 0..32767
    const int mat  = s >> 13;
    const int h    = (s >> 10) & 7;
    const int t    = (s >> 9) & 1;
    const int kk   = (s >> 6) & 7;
    const int lane = s & 63;
    const int l15  = lane & 15;
    const int g    = lane >> 4;
    const float* src = (mat == 0) ? wq : (mat == 1) ? wk : (mat == 2) ? wv : wo;
    const int n  = h * 32 + t * 16 + l15;
    const int k0 = kk * 32 + g * 8;
    unsigned short* dst = wt + (size_t)s * 8;
#pragma unroll
    for (int j = 0; j < 8; ++j)
        dst[j] = f2bf(src[(k0 + j) * 256 + n]);
}

// ---------------- fused window attention, register-resident attention ----------------
// grid = 1024 (= 16 b * 64 h), block = 512 (8 waves). Each WG owns 64 tokens.
// wave w = head w. Xs fragment-linear in LDS (r18: conflicts 5.2M->1.05M).
// W-fragment loads pipelined 1-deep in program order (r15). Os overlays Xs.
// s_setprio(1) around each MFMA cluster (T5) — the one new variable vs r18.
#define XS_STRIDE 264   // Os row stride (256 + 8 pad shorts)

__global__ __launch_bounds__(512, 4) void win_attn(
    const float* __restrict__ x,
    const unsigned short* __restrict__ wt,   // fragment-linear weights (512 KiB)
    const float* __restrict__ bo,
    float* __restrict__ out)                 // f32 output
{
    __shared__ unsigned short lds[16896];    // 33 KiB: XsF (32 KiB) / Os overlay
    unsigned short* XsF = lds;               // fragment-linear: slot*8 shorts
    unsigned short* Os  = lds;               // [64][264] (after phase-3 barrier)

    const int tid  = threadIdx.x;
    const int wid  = tid >> 6;               // 0..7 (= head)
    const int lane = tid & 63;
    const int l15  = lane & 15;
    const int g    = lane >> 4;              // 0..3

    const bf16x8* WF = reinterpret_cast<const bf16x8*>(wt);
    // weight fragment index: (((mat*8 + wid)*2 + t)*8 + kk)*64 + lane
    const int wbase = (wid * 2) * 8 * 64 + lane;
#define WFRAG(mat, t, kk) WF[(mat) * 8192 + wbase + ((t) * 8 + (kk)) * 64]
    // X fragment (nt = token-tile 0..3, kk = 0..7): A/B-operand rows token-major
#define XFRAG(nt, kk) (*reinterpret_cast<const bf16x8*>(&XsF[(((nt) * 8 + (kk)) * 64 + lane) * 8]))

    const long long base_tok = (long long)blockIdx.x * 64;
    const float* xblk = x + base_tok * 256;

    const f32x4 fz = {0.f, 0.f, 0.f, 0.f};

    // ---- phase 0: stage x block directly in fragment-linear bf16 layout ----
    // slot s -> row = nt*16 + (s&15), col chunk = kk*32 + ((s>>4)&3)*8 (8 floats)
#pragma unroll
    for (int i = 0; i < 4; ++i) {
        int s    = tid + i * 512;            // 0..2047
        int ls   = s & 63;
        int frag = s >> 6;                   // nt*8 + kk
        int row  = (frag >> 3) * 16 + (ls & 15);
        int col  = (frag & 7) * 32 + (ls >> 4) * 8;
        const float4* src = reinterpret_cast<const float4*>(&xblk[row * 256 + col]);
        float4 lo = src[0], hi = src[1];
        bf16x8 w;
        w[0] = (short)f2bf(lo.x); w[1] = (short)f2bf(lo.y);
        w[2] = (short)f2bf(lo.z); w[3] = (short)f2bf(lo.w);
        w[4] = (short)f2bf(hi.x); w[5] = (short)f2bf(hi.y);
        w[6] = (short)f2bf(hi.z); w[7] = (short)f2bf(hi.w);
        *reinterpret_cast<bf16x8*>(&XsF[s * 8]) = w;
    }
    __syncthreads();

    // ---- phase 1: V = X Wv, one d-half at a time -> PV B-frags ----
    // lane: d = dh*16 + l15, token = mi*16 + 4g + r
    bf16x8 vtf[2][2];                            // [k-half][d-half]
#pragma unroll
    for (int dh = 0; dh < 2; ++dh) {
        f32x4 vac[4] = {fz, fz, fz, fz};
        bf16x8 bvc = WFRAG(2, dh, 0);            // pipeline prologue
        prio_hi();
#pragma unroll
        for (int kk = 0; kk < 8; ++kk) {
            bf16x8 bvn = bvc;
            if (kk < 7) bvn = WFRAG(2, dh, kk + 1);   // issue next BEFORE cluster
#pragma unroll
            for (int mi = 0; mi < 4; ++mi)
                vac[mi] = mfma_bf16(XFRAG(mi, kk), bvc, vac[mi]);
            bvc = bvn;
        }
        prio_lo();
        mfma_fence();
        vtf[0][dh] = pack2(vac[0], vac[1]);
        vtf[1][dh] = pack2(vac[2], vac[3]);
    }

    // ---- phase 2: Q^T = mfma(A = Wq-frag (m=d), B = X-frag (n=token)) ----
    // lane: token = nt*16 + l15, d = mt*16 + 4g + r
    bf16x8 qtf[4];
    {
        f32x4 qt[2][4] = {{fz, fz, fz, fz}, {fz, fz, fz, fz}};
        bf16x8 awc0 = WFRAG(0, 0, 0), awc1 = WFRAG(0, 1, 0);
        prio_hi();
#pragma unroll
        for (int kk = 0; kk < 8; ++kk) {
            bf16x8 awn0 = awc0, awn1 = awc1;
            if (kk < 7) { awn0 = WFRAG(0, 0, kk + 1); awn1 = WFRAG(0, 1, kk + 1); }
#pragma unroll
            for (int nt = 0; nt < 4; ++nt) {
                bf16x8 bx = XFRAG(nt, kk);
                qt[0][nt] = mfma_bf16(awc0, bx, qt[0][nt]);
                qt[1][nt] = mfma_bf16(awc1, bx, qt[1][nt]);
            }
            awc0 = awn0; awc1 = awn1;
        }
        prio_lo();
        mfma_fence();
#pragma unroll
        for (int nt = 0; nt < 4; ++nt) qtf[nt] = pack2(qt[0][nt], qt[1][nt]);
    }

    // ---- phase 3: K^T, same structure ----
    bf16x8 ktf[4];
    {
        f32x4 kt[2][4] = {{fz, fz, fz, fz}, {fz, fz, fz, fz}};
        bf16x8 awc0 = WFRAG(1, 0, 0), awc1 = WFRAG(1, 1, 0);
        prio_hi();
#pragma unroll
        for (int kk = 0; kk < 8; ++kk) {
            bf16x8 awn0 = awc0, awn1 = awc1;
            if (kk < 7) { awn0 = WFRAG(1, 0, kk + 1); awn1 = WFRAG(1, 1, kk + 1); }
#pragma unroll
            for (int nt = 0; nt < 4; ++nt) {
                bf16x8 bx = XFRAG(nt, kk);
                kt[0][nt] = mfma_bf16(awc0, bx, kt[0][nt]);
                kt[1][nt] = mfma_bf16(awc1, bx, kt[1][nt]);
            }
            awc0 = awn0; awc1 = awn1;
        }
        prio_lo();
        mfma_fence();
#pragma unroll
        for (int nt = 0; nt < 4; ++nt) ktf[nt] = pack2(kt[0][nt], kt[1][nt]);
    }

    __syncthreads();   // all XsF reads done before Os (same memory) is written

    // ---- phase 4: per q-tile ni: S^T = K Q^T, softmax over k_tok, pa, PV, Os ----
    // st[mi]: lane -> k_tok = mi*16 + 4g + r, q = ni*16 + l15
    constexpr float kC = 0.25501817419392105f;  // (1/sqrt(32)) * log2(e)
#pragma unroll
    for (int ni = 0; ni < 4; ++ni) {
        f32x4 st[4];
        prio_hi();
#pragma unroll
        for (int mi = 0; mi < 4; ++mi)
            st[mi] = mfma_bf16(ktf[mi], qtf[ni], fz);
        prio_lo();
        mfma_fence();
        float m = st[0][0];
#pragma unroll
        for (int mi = 0; mi < 4; ++mi)
#pragma unroll
            for (int r = 0; r < 4; ++r) m = fmaxf(m, st[mi][r]);
        m = fmaxf(m, __shfl_xor(m, 16));
        m = fmaxf(m, __shfl_xor(m, 32));
        float sum = 0.f;
#pragma unroll
        for (int mi = 0; mi < 4; ++mi)
#pragma unroll
            for (int r = 0; r < 4; ++r) {
                st[mi][r] = exp2f((st[mi][r] - m) * kC);   // in place
                sum += st[mi][r];
            }
        sum += __shfl_xor(sum, 16);
        sum += __shfl_xor(sum, 32);
        float inv = 1.0f / sum;
        bf16x8 pa[2];                            // P fragment for THIS q-tile only
#pragma unroll
        for (int kk = 0; kk < 2; ++kk) {
            bf16x8 t;
#pragma unroll
            for (int j = 0; j < 4; ++j) {
                t[j]     = (short)f2bf(st[2 * kk][j] * inv);
                t[4 + j] = (short)f2bf(st[2 * kk + 1][j] * inv);
            }
            pa[kk] = t;
        }
        f32x4 oacc[2] = {fz, fz};
        prio_hi();
#pragma unroll
        for (int kk = 0; kk < 2; ++kk)
#pragma unroll
            for (int dh = 0; dh < 2; ++dh)
                oacc[dh] = mfma_bf16(pa[kk], vtf[kk][dh], oacc[dh]);
        prio_lo();
        mfma_fence();
#pragma unroll
        for (int dh = 0; dh < 2; ++dh)
#pragma unroll
            for (int r = 0; r < 4; ++r)
                Os[(ni * 16 + g * 4 + r) * XS_STRIDE + wid * 32 + dh * 16 + l15] = f2bf(oacc[dh][r]);
    }
    __syncthreads();

    // ---- phase 5: Y = Os @ Wo + bo, f32 store ----
    {
        f32x4 yacc[4][2] = {{fz, fz}, {fz, fz}, {fz, fz}, {fz, fz}};
        bf16x8 bc0 = WFRAG(3, 0, 0), bc1 = WFRAG(3, 1, 0);
        prio_hi();
#pragma unroll
        for (int kk = 0; kk < 8; ++kk) {
            bf16x8 bn0 = bc0, bn1 = bc1;
            if (kk < 7) { bn0 = WFRAG(3, 0, kk + 1); bn1 = WFRAG(3, 1, kk + 1); }
            bf16x8 a[4];
#pragma unroll
            for (int mi = 0; mi < 4; ++mi)
                a[mi] = *reinterpret_cast<const bf16x8*>(&Os[(mi * 16 + l15) * XS_STRIDE + kk * 32 + g * 8]);
#pragma unroll
            for (int mi = 0; mi < 4; ++mi) {
                yacc[mi][0] = mfma_bf16(a[mi], bc0, yacc[mi][0]);
                yacc[mi][1] = mfma_bf16(a[mi], bc1, yacc[mi][1]);
            }
            bc0 = bn0; bc1 = bn1;
        }
        prio_lo();
        mfma_fence();
#pragma unroll
        for (int mi = 0; mi < 4; ++mi) {
#pragma unroll
            for (int ni = 0; ni < 2; ++ni) {
                int col = wid * 32 + ni * 16 + l15;
                float bv = bo[col];
#pragma unroll
                for (int r = 0; r < 4; ++r) {
                    int row = mi * 16 + g * 4 + r;
                    out[(base_tok + row) * 256 + col] = yacc[mi][ni][r] + bv;
                }
            }
        }
    }
#undef XFRAG
#undef WFRAG
}

extern "C" void kernel_launch(void* const* d_in, const int* in_sizes, int n_in,
                              void* d_out, int out_size, void* d_ws, size_t ws_size,
                              hipStream_t stream) {
    const float* x  = (const float*)d_in[0];
    const float* wq = (const float*)d_in[1];
    const float* wk = (const float*)d_in[2];
    const float* wv = (const float*)d_in[3];
    const float* wo = (const float*)d_in[4];
    const float* bo = (const float*)d_in[5];
    unsigned short* wt = (unsigned short*)d_ws;      // 4 * 256*256 bf16 = 512 KiB
    float* out = (float*)d_out;                      // f32 output

    prep_weights<<<128, 256, 0, stream>>>(wq, wk, wv, wo, wt);
    win_attn<<<1024, 512, 0, stream>>>(x, wt, bo, out);
}

// Round 22
// 66.191 us; speedup vs baseline: 1.0162x; 1.0162x over previous
//
#include <hip/hip_runtime.h>
#include <hip/hip_bf16.h>

typedef short bf16x8 __attribute__((ext_vector_type(8)));
typedef float f32x4  __attribute__((ext_vector_type(4)));

__device__ __forceinline__ unsigned short f2bf(float f) {
    union { __hip_bfloat16 b; unsigned short u; } v;
    v.b = __hip_bfloat16(f);          // native RNE cvt (pairs into v_cvt_pk_bf16_f32)
    return v.u;
}

// MFMA pinned to arch VGPRs via inline asm -> zero AGPRs -> the full
// __launch_bounds__ budget is arch registers (r13: no spill, 2 WG/CU).
// VOLATILE is load-bearing (r14: non-volatile -> scheduler sank MFMAs -> NaN).
// s_nop 1 embedded covers compiler-inserted VALU writes before the MFMA (r12).
// (512,4) is load-bearing: (512,8)'s 64-reg cap forced mid-cluster spills whose
// scratch code is hazard-unprotected around asm MFMAs (r17: absmax 1.27;
// r19/r21: same signature whenever any phase's ledger exceeds ~120).
__device__ __forceinline__ f32x4 mfma_bf16(bf16x8 a, bf16x8 b, f32x4 c) {
    asm volatile("s_nop 1\n\tv_mfma_f32_16x16x32_bf16 %0, %1, %2, %0"
                 : "+v"(c) : "v"(a), "v"(b));
    return c;
}

// Cluster-boundary fence: 16 wait states >= MFMA-write -> VALU-read hazard.
__device__ __forceinline__ void mfma_fence() {
    __builtin_amdgcn_sched_barrier(0);
    asm volatile("s_nop 7\n\ts_nop 7");
    __builtin_amdgcn_sched_barrier(0);
}

// pack two f32x4 acc tiles (m-tile 0, m-tile 1) into one bf16 fragment under
// the shared k-bijection pi(g,j) = {4g+j | j<4} u {16+4g+(j-4) | j>=4}
__device__ __forceinline__ bf16x8 pack2(f32x4 lo, f32x4 hi) {
    bf16x8 r;
    r[0] = (short)f2bf(lo[0]); r[1] = (short)f2bf(lo[1]);
    r[2] = (short)f2bf(lo[2]); r[3] = (short)f2bf(lo[3]);
    r[4] = (short)f2bf(hi[0]); r[5] = (short)f2bf(hi[1]);
    r[6] = (short)f2bf(hi[2]); r[7] = (short)f2bf(hi[3]);
    return r;
}

// ---------------- prep: weights -> MFMA-fragment-linear bf16 layout ----------------
// slot s = (((mat*8 + h)*2 + t)*8 + kk)*64 + lane ; each slot = 8 bf16 (16 B).
// content: W[k][n] for n = h*32 + t*16 + (lane&15), k = kk*32 + (lane>>4)*8 + j.
__global__ __launch_bounds__(256) void prep_weights(
    const float* __restrict__ wq, const float* __restrict__ wk,
    const float* __restrict__ wv, const float* __restrict__ wo,
    unsigned short* __restrict__ wt)
{
    const int s = blockIdx.x * 256 + threadIdx.x;   // 0..32767
    const int mat  = s >> 13;
    const int h    = (s >> 10) & 7;
    const int t    = (s >> 9) & 1;
    const int kk   = (s >> 6) & 7;
    const int lane = s & 63;
    const int l15  = lane & 15;
    const int g    = lane >> 4;
    const float* src = (mat == 0) ? wq : (mat == 1) ? wk : (mat == 2) ? wv : wo;
    const int n  = h * 32 + t * 16 + l15;
    const int k0 = kk * 32 + g * 8;
    unsigned short* dst = wt + (size_t)s * 8;
#pragma unroll
    for (int j = 0; j < 8; ++j)
        dst[j] = f2bf(src[(k0 + j) * 256 + n]);
}

// ---------------- fused window attention, register-resident attention ----------------
// grid = 1024 (= 16 b * 64 h), block = 512 (8 waves). Each WG owns 64 tokens.
// wave w = head w. SEQUENTIAL projections (V per-d-half -> Q^T -> K^T), zero
// AGPRs -> (512,4) 128-reg arch budget -> 2 WGs/CU. W-fragment loads are
// software-pipelined 1-deep IN PROGRAM ORDER (kk+1's loads before kk's volatile
// MFMA cluster) so their L2 latency hides under the MFMAs.
// FINAL (r22 = r15 revert): best verified configuration. The structure's
// scheduling plateau is ~62-67 us (MfmaUtil ~25%): six isolated levers (bank
// conflicts -80%, W/X rotation, LDS halving 66->33 KiB, setprio, occupancy
// bounds) each moved <3%. Register regime forbids deeper pipelining (r17/r19/
// r21: any phase ledger >~120 regs spills, and spill code around asm MFMA is
// hazard-unprotected -> silent corruption). Past this point requires a
// different kernel architecture (32x32 MFMA remap or kernel split).
#define XS_STRIDE 264   // 256 + 8 pad shorts

__global__ __launch_bounds__(512, 4) void win_attn(
    const float* __restrict__ x,
    const unsigned short* __restrict__ wt,   // fragment-linear weights (512 KiB)
    const float* __restrict__ bo,
    float* __restrict__ out)                 // f32 output
{
    __shared__ unsigned short lds[33792];    // 66 KiB
    unsigned short* Xs = lds;                // [64][264]
    unsigned short* Os = lds + 16896;        // [64][264]

    const int tid  = threadIdx.x;
    const int wid  = tid >> 6;               // 0..7 (= head)
    const int lane = tid & 63;
    const int l15  = lane & 15;
    const int g    = lane >> 4;              // 0..3

    const bf16x8* WF = reinterpret_cast<const bf16x8*>(wt);
    // fragment index: (((mat*8 + wid)*2 + t)*8 + kk)*64 + lane
    const int wbase = (wid * 2) * 8 * 64 + lane;
#define WFRAG(mat, t, kk) WF[(mat) * 8192 + wbase + ((t) * 8 + (kk)) * 64]

    const long long base_tok = (long long)blockIdx.x * 64;
    const float* xblk = x + base_tok * 256;

    const f32x4 fz = {0.f, 0.f, 0.f, 0.f};

    // ---- phase 0: stage x row-block as bf16 in LDS ----
#pragma unroll
    for (int i = 0; i < 8; ++i) {
        int p   = tid + i * 512;             // float4 index, 0..4095
        int tok = p >> 6;
        int col = (p & 63) * 4;
        float4 v = reinterpret_cast<const float4*>(xblk)[p];
        ushort4 h;
        h.x = f2bf(v.x); h.y = f2bf(v.y); h.z = f2bf(v.z); h.w = f2bf(v.w);
        *reinterpret_cast<ushort4*>(&Xs[tok * XS_STRIDE + col]) = h;
    }
    __syncthreads();

    // ---- phase 1: V = X Wv, one d-half at a time -> PV B-frags ----
    // lane: d = dh*16 + l15, token = mi*16 + 4g + r
    bf16x8 vtf[2][2];                            // [k-half][d-half]
#pragma unroll
    for (int dh = 0; dh < 2; ++dh) {
        f32x4 vac[4] = {fz, fz, fz, fz};
        bf16x8 bvc = WFRAG(2, dh, 0);            // pipeline prologue
#pragma unroll
        for (int kk = 0; kk < 8; ++kk) {
            bf16x8 bvn = bvc;
            if (kk < 7) bvn = WFRAG(2, dh, kk + 1);   // issue next BEFORE cluster
#pragma unroll
            for (int mi = 0; mi < 4; ++mi) {
                bf16x8 a = *reinterpret_cast<const bf16x8*>(&Xs[(mi * 16 + l15) * XS_STRIDE + kk * 32 + g * 8]);
                vac[mi] = mfma_bf16(a, bvc, vac[mi]);
            }
            bvc = bvn;
        }
        mfma_fence();
        vtf[0][dh] = pack2(vac[0], vac[1]);
        vtf[1][dh] = pack2(vac[2], vac[3]);
    }

    // ---- phase 2: Q^T = mfma(A = Wq-frag (m=d), B = Xs rows (n=token)) ----
    // lane: token = nt*16 + l15, d = mt*16 + 4g + r
    bf16x8 qtf[4];
    {
        f32x4 qt[2][4] = {{fz, fz, fz, fz}, {fz, fz, fz, fz}};
        bf16x8 awc0 = WFRAG(0, 0, 0), awc1 = WFRAG(0, 1, 0);
#pragma unroll
        for (int kk = 0; kk < 8; ++kk) {
            bf16x8 awn0 = awc0, awn1 = awc1;
            if (kk < 7) { awn0 = WFRAG(0, 0, kk + 1); awn1 = WFRAG(0, 1, kk + 1); }
            bf16x8 bx[4];
#pragma unroll
            for (int nt = 0; nt < 4; ++nt)
                bx[nt] = *reinterpret_cast<const bf16x8*>(&Xs[(nt * 16 + l15) * XS_STRIDE + kk * 32 + g * 8]);
#pragma unroll
            for (int nt = 0; nt < 4; ++nt) {
                qt[0][nt] = mfma_bf16(awc0, bx[nt], qt[0][nt]);
                qt[1][nt] = mfma_bf16(awc1, bx[nt], qt[1][nt]);
            }
            awc0 = awn0; awc1 = awn1;
        }
        mfma_fence();
#pragma unroll
        for (int nt = 0; nt < 4; ++nt) qtf[nt] = pack2(qt[0][nt], qt[1][nt]);
    }

    // ---- phase 3: K^T, same structure ----
    bf16x8 ktf[4];
    {
        f32x4 kt[2][4] = {{fz, fz, fz, fz}, {fz, fz, fz, fz}};
        bf16x8 awc0 = WFRAG(1, 0, 0), awc1 = WFRAG(1, 1, 0);
#pragma unroll
        for (int kk = 0; kk < 8; ++kk) {
            bf16x8 awn0 = awc0, awn1 = awc1;
            if (kk < 7) { awn0 = WFRAG(1, 0, kk + 1); awn1 = WFRAG(1, 1, kk + 1); }
            bf16x8 bx[4];
#pragma unroll
            for (int nt = 0; nt < 4; ++nt)
                bx[nt] = *reinterpret_cast<const bf16x8*>(&Xs[(nt * 16 + l15) * XS_STRIDE + kk * 32 + g * 8]);
#pragma unroll
            for (int nt = 0; nt < 4; ++nt) {
                kt[0][nt] = mfma_bf16(awc0, bx[nt], kt[0][nt]);
                kt[1][nt] = mfma_bf16(awc1, bx[nt], kt[1][nt]);
            }
            awc0 = awn0; awc1 = awn1;
        }
        mfma_fence();
#pragma unroll
        for (int nt = 0; nt < 4; ++nt) ktf[nt] = pack2(kt[0][nt], kt[1][nt]);
    }

    // ---- phase 4: per q-tile ni: S^T = K Q^T, softmax over k_tok, pa, PV, Os ----
    // st[mi]: lane -> k_tok = mi*16 + 4g + r, q = ni*16 + l15
    constexpr float kC = 0.25501817419392105f;  // (1/sqrt(32)) * log2(e)
#pragma unroll
    for (int ni = 0; ni < 4; ++ni) {
        f32x4 st[4];
#pragma unroll
        for (int mi = 0; mi < 4; ++mi)
            st[mi] = mfma_bf16(ktf[mi], qtf[ni], fz);
        mfma_fence();
        float m = st[0][0];
#pragma unroll
        for (int mi = 0; mi < 4; ++mi)
#pragma unroll
            for (int r = 0; r < 4; ++r) m = fmaxf(m, st[mi][r]);
        m = fmaxf(m, __shfl_xor(m, 16));
        m = fmaxf(m, __shfl_xor(m, 32));
        float sum = 0.f;
#pragma unroll
        for (int mi = 0; mi < 4; ++mi)
#pragma unroll
            for (int r = 0; r < 4; ++r) {
                st[mi][r] = exp2f((st[mi][r] - m) * kC);   // in place
                sum += st[mi][r];
            }
        sum += __shfl_xor(sum, 16);
        sum += __shfl_xor(sum, 32);
        float inv = 1.0f / sum;
        bf16x8 pa[2];                            // P fragment for THIS q-tile only
#pragma unroll
        for (int kk = 0; kk < 2; ++kk) {
            bf16x8 t;
#pragma unroll
            for (int j = 0; j < 4; ++j) {
                t[j]     = (short)f2bf(st[2 * kk][j] * inv);
                t[4 + j] = (short)f2bf(st[2 * kk + 1][j] * inv);
            }
            pa[kk] = t;
        }
        f32x4 oacc[2] = {fz, fz};
#pragma unroll
        for (int kk = 0; kk < 2; ++kk)
#pragma unroll
            for (int dh = 0; dh < 2; ++dh)
                oacc[dh] = mfma_bf16(pa[kk], vtf[kk][dh], oacc[dh]);
        mfma_fence();
#pragma unroll
        for (int dh = 0; dh < 2; ++dh)
#pragma unroll
            for (int r = 0; r < 4; ++r)
                Os[(ni * 16 + g * 4 + r) * XS_STRIDE + wid * 32 + dh * 16 + l15] = f2bf(oacc[dh][r]);
    }
    __syncthreads();

    // ---- phase 5: Y = Os @ Wo + bo, f32 store ----
    {
        f32x4 yacc[4][2] = {{fz, fz}, {fz, fz}, {fz, fz}, {fz, fz}};
        bf16x8 bc0 = WFRAG(3, 0, 0), bc1 = WFRAG(3, 1, 0);
#pragma unroll
        for (int kk = 0; kk < 8; ++kk) {
            bf16x8 bn0 = bc0, bn1 = bc1;
            if (kk < 7) { bn0 = WFRAG(3, 0, kk + 1); bn1 = WFRAG(3, 1, kk + 1); }
            bf16x8 a[4];
#pragma unroll
            for (int mi = 0; mi < 4; ++mi)
                a[mi] = *reinterpret_cast<const bf16x8*>(&Os[(mi * 16 + l15) * XS_STRIDE + kk * 32 + g * 8]);
#pragma unroll
            for (int mi = 0; mi < 4; ++mi) {
                yacc[mi][0] = mfma_bf16(a[mi], bc0, yacc[mi][0]);
                yacc[mi][1] = mfma_bf16(a[mi], bc1, yacc[mi][1]);
            }
            bc0 = bn0; bc1 = bn1;
        }
        mfma_fence();
#pragma unroll
        for (int mi = 0; mi < 4; ++mi) {
#pragma unroll
            for (int ni = 0; ni < 2; ++ni) {
                int col = wid * 32 + ni * 16 + l15;
                float bv = bo[col];
#pragma unroll
                for (int r = 0; r < 4; ++r) {
                    int row = mi * 16 + g * 4 + r;
                    out[(base_tok + row) * 256 + col] = yacc[mi][ni][r] + bv;
                }
            }
        }
    }
#undef WFRAG
}

extern "C" void kernel_launch(void* const* d_in, const int* in_sizes, int n_in,
                              void* d_out, int out_size, void* d_ws, size_t ws_size,
                              hipStream_t stream) {
    const float* x  = (const float*)d_in[0];
    const float* wq = (const float*)d_in[1];
    const float* wk = (const float*)d_in[2];
    const float* wv = (const float*)d_in[3];
    const float* wo = (const float*)d_in[4];
    const float* bo = (const float*)d_in[5];
    unsigned short* wt = (unsigned short*)d_ws;      // 4 * 256*256 bf16 = 512 KiB
    float* out = (float*)d_out;                      // f32 output

    prep_weights<<<128, 256, 0, stream>>>(wq, wk, wv, wo, wt);
    win_attn<<<1024, 512, 0, stream>>>(x, wt, bo, out);
}